// Round 3
// baseline (214.805 us; speedup 1.0000x reference)
//
#include <hip/hip_runtime.h>

typedef __bf16 bf16x8 __attribute__((ext_vector_type(8)));
typedef float f32x4 __attribute__((ext_vector_type(4)));

__device__ __forceinline__ unsigned short f2bf(float f) {
    unsigned int u = __builtin_bit_cast(unsigned int, f);
    u += 0x7fffu + ((u >> 16) & 1u);   // round-to-nearest-even (finite inputs)
    return (unsigned short)(u >> 16);
}

// ---- Kernel 1: s_eff[b][i] = (style[b]·affine_w[i]/sqrt(S) + affine_b[i]) * wg ----
__global__ void k_style(const float* __restrict__ style, const float* __restrict__ aw,
                        const float* __restrict__ ab, float* __restrict__ s_eff) {
    int b = blockIdx.x;
    int i = threadIdx.x;          // 512 threads
    __shared__ float st[512];
    st[i] = style[(b << 9) + i];
    __syncthreads();
    const float4* row = (const float4*)(aw + ((size_t)i << 9));
    float acc = 0.f;
#pragma unroll 4
    for (int k = 0; k < 128; ++k) {
        float4 r = row[k];
        acc += r.x * st[4 * k] + r.y * st[4 * k + 1] + r.z * st[4 * k + 2] + r.w * st[4 * k + 3];
    }
    float s = acc * 0.04419417382415922f + ab[i];     // 1/sqrt(512)
    s_eff[(b << 9) + i] = s * 0.014731391274719739f;  // wg = 1/sqrt(512*9)
}

// ---- Kernel 2: zero ONLY the padding border of xmod (260 cells/b x 512 ch) ----
__global__ __launch_bounds__(256) void k_border(unsigned short* __restrict__ xmod) {
    int idx = blockIdx.x * 256 + threadIdx.x;   // 0..66559  (4*260*64)
    int cell = idx >> 6, sub = idx & 63;
    int b = cell / 260, c = cell - b * 260;
    int row, col;
    if (c < 66)       { row = 0;  col = c; }
    else if (c < 132) { row = 65; col = c - 66; }
    else { int d = c - 132; row = 1 + (d >> 1); col = (d & 1) * 65; }
    uint4 z; z.x = z.y = z.z = z.w = 0u;
    *(uint4*)(xmod + (((size_t)(b * 66 + row) * 66 + col) << 9) + (sub << 3)) = z;
}

// ---- Kernel 3: x (NCHW f32) -> xmod (padded NHWC bf16), modulated by s_eff ----
// xmod layout: [B][66][66][512] bf16, interior at [h+1][w+1]
__global__ __launch_bounds__(256) void k_packx(const float* __restrict__ x,
                                               const float* __restrict__ s_eff,
                                               unsigned short* __restrict__ xmod) {
    int b = blockIdx.z, h = blockIdx.y, i0 = blockIdx.x << 6;
    __shared__ unsigned short tile[64][72];
    int t = threadIdx.x;
    int w4 = (t & 15) << 2;      // w base: 0,4,...,60
    int ig = t >> 4;             // 0..15
#pragma unroll
    for (int r = 0; r < 4; ++r) {
        int il = (r << 4) + ig;
        int i = i0 + il;
        float4 v = *(const float4*)(x + (size_t)((((b << 9) + i) << 6) + h) * 64 + w4);
        float s = s_eff[(b << 9) + i];
        union { unsigned short us[4]; uint2 u2; } u;
        u.us[0] = f2bf(v.x * s); u.us[1] = f2bf(v.y * s);
        u.us[2] = f2bf(v.z * s); u.us[3] = f2bf(v.w * s);
        *(uint2*)&tile[il][w4] = u.u2;
    }
    __syncthreads();
    int ib = (t & 7) << 3;   // channel sub-block (8 bf16 = 16B)
    int wb = t >> 3;         // 0..31
#pragma unroll
    for (int pass = 0; pass < 2; ++pass) {
        int w = wb + (pass << 5);
        union { unsigned short us[8]; uint4 v; } u;
#pragma unroll
        for (int j = 0; j < 8; ++j) u.us[j] = tile[ib + j][w];
        *(uint4*)(xmod + (((size_t)(b * 66 + h + 1) * 66 + (w + 1)) << 9) + i0 + ib) = u.v;
    }
}

// ---- Kernel 4: weight (O,I,3,3 f32) -> wpk (O,9,I bf16) ----
__global__ __launch_bounds__(256) void k_packw(const float* __restrict__ wsrc,
                                               unsigned short* __restrict__ wpk) {
    int o = blockIdx.x;
    for (int i = threadIdx.x; i < 512; i += 256) {
        const float* src = wsrc + (size_t)((o << 9) + i) * 9;
#pragma unroll
        for (int r = 0; r < 9; ++r)
            wpk[((o * 9 + r) << 9) + i] = f2bf(src[r]);
    }
}

// ---- Kernel 5: implicit GEMM conv. ----
// Block tile 128(O) x 128(N=2 rows x 64 w), 4 waves (2x2), 16x16x32 bf16 MFMA.
// A (weights) read DIRECTLY global->reg (L2-resident, line-coalesced): no A-LDS, no per-tap barriers.
// B (xmod) double-buffered in LDS with early-issued reg prefetch (T14 split): 1 barrier / 32-ch chunk.
__global__ __launch_bounds__(256) void k_conv(const unsigned short* __restrict__ xmod,
                                              const unsigned short* __restrict__ wpk,
                                              float* __restrict__ out) {
    __shared__ __attribute__((aligned(128))) unsigned char lds[2][21120];  // 4 rows x 66 cols x 80B
    int bid = blockIdx.x;
    // XCD swizzle: xcd = bid&7 owns contiguous swz chunk; mt = swz>>7 -> 2 XCDs per m-tile (wpk L2-resident)
    int swz = ((bid & 7) << 6) | (bid >> 3);
    int mt = swz >> 7, nt = swz & 127;
    int b = nt >> 5, h0 = (nt & 31) << 1;
    int m0 = mt << 7;
    int tid = threadIdx.x;
    int lane = tid & 63;
    int wv = tid >> 6;
    int wave_m = wv & 1, wave_n = wv >> 1;
    int lm = lane & 15, lk = lane >> 4;

    // per-thread B staging slots: 1056 16B-chunks over 256 threads (tid<32 get 5)
    int ldsoff[5]; long goff[5];
    int nch = (tid < 32) ? 5 : 4;
#pragma unroll
    for (int q = 0; q < 5; ++q) {
        int c = tid + (q << 8);
        int cl = c >> 2, sub = c & 3;
        int row = cl / 66, col = cl - row * 66;
        ldsoff[q] = row * 5280 + col * 80 + (sub << 4);
        goff[q] = (long)(((b * 66 + h0 + row) * 66 + col) << 9) + (sub << 3);
    }

    f32x4 acc[4][4] = {};
    uint4 pre[5];

    // prologue: stage B(ch 0..31) -> buf0; prefetch B(ch 32..63) to regs
#pragma unroll
    for (int q = 0; q < 5; ++q) if (q < nch) pre[q] = *(const uint4*)(xmod + goff[q]);
#pragma unroll
    for (int q = 0; q < 5; ++q) if (q < nch) *(uint4*)(&lds[0][0] + ldsoff[q]) = pre[q];
#pragma unroll
    for (int q = 0; q < 5; ++q) if (q < nch) pre[q] = *(const uint4*)(xmod + goff[q] + 32);
    __syncthreads();

    // weight base for this lane: row (m0 + wave_m*64 + lm), ch sub-chunk lk*8
    const unsigned short* wrow = wpk + (size_t)(m0 + (wave_m << 6) + lm) * 4608 + (lk << 3);

    for (int ic = 0; ic < 16; ++ic) {
        const unsigned char* bufc = &lds[ic & 1][0];
        const unsigned short* wic = wrow + (ic << 5);
#pragma unroll
        for (int r = 0; r < 9; ++r) {
            int kh = r / 3, kw = r - kh * 3;
            bf16x8 af[4], bfr[4];
#pragma unroll
            for (int fm = 0; fm < 4; ++fm)
                af[fm] = *(const bf16x8*)(wic + fm * 16 * 4608 + r * 512);
#pragma unroll
            for (int fn = 0; fn < 4; ++fn) {
                int nl = (wave_n << 6) + (fn << 4) + lm;
                int hl = nl >> 6, w = nl & 63;
                bfr[fn] = *(const bf16x8*)(bufc + (hl + kh) * 5280 + (w + kw) * 80 + (lk << 4));
            }
#pragma unroll
            for (int fm = 0; fm < 4; ++fm)
#pragma unroll
                for (int fn = 0; fn < 4; ++fn)
                    acc[fm][fn] = __builtin_amdgcn_mfma_f32_16x16x32_bf16(af[fm], bfr[fn], acc[fm][fn], 0, 0, 0);
        }
        if (ic < 15) {
            unsigned char* bufn = &lds[(ic + 1) & 1][0];
#pragma unroll
            for (int q = 0; q < 5; ++q) if (q < nch) *(uint4*)(bufn + ldsoff[q]) = pre[q];
            if (ic < 14) {
#pragma unroll
                for (int q = 0; q < 5; ++q) if (q < nch) pre[q] = *(const uint4*)(xmod + goff[q] + ((ic + 2) << 5));
            }
        }
        __syncthreads();
    }

    // epilogue: D row=(lk*4+rr) is O-sub, col=lm is N
#pragma unroll
    for (int fm = 0; fm < 4; ++fm) {
        int o = m0 + (wave_m << 6) + (fm << 4) + (lk << 2);
#pragma unroll
        for (int fn = 0; fn < 4; ++fn) {
            int nl = (wave_n << 6) + (fn << 4) + lm;
            int hl = nl >> 6, w = nl & 63;
            float* dst = out + ((((b << 9) + o) << 6) + (h0 + hl)) * 64 + w;
#pragma unroll
            for (int rr = 0; rr < 4; ++rr)
                dst[rr * 4096] = acc[fm][fn][rr];
        }
    }
}

extern "C" void kernel_launch(void* const* d_in, const int* in_sizes, int n_in,
                              void* d_out, int out_size, void* d_ws, size_t ws_size,
                              hipStream_t stream) {
    const float* x      = (const float*)d_in[0];
    const float* style  = (const float*)d_in[1];
    const float* weight = (const float*)d_in[2];
    const float* aff_w  = (const float*)d_in[3];
    const float* aff_b  = (const float*)d_in[4];
    float* out = (float*)d_out;

    // workspace layout
    unsigned short* xmod = (unsigned short*)d_ws;      // 4*66*66*512 = 8,921,088 bf16 (17.8 MB)
    unsigned short* wpk  = xmod + 8921088;             // 512*9*512  = 2,359,296 bf16 (4.7 MB)
    float* s_eff = (float*)((char*)d_ws + 22560768);   // 2048 f32

    hipLaunchKernelGGL(k_style, dim3(4), dim3(512), 0, stream, style, aff_w, aff_b, s_eff);
    hipLaunchKernelGGL(k_border, dim3(260), dim3(256), 0, stream, xmod);
    hipLaunchKernelGGL(k_packx, dim3(8, 64, 4), dim3(256), 0, stream, x, s_eff, xmod);
    hipLaunchKernelGGL(k_packw, dim3(512), dim3(256), 0, stream, weight, wpk);
    hipLaunchKernelGGL(k_conv, dim3(512), dim3(256), 0, stream, xmod, wpk, out);
}

// Round 5
// 119.051 us; speedup vs baseline: 1.8043x; 1.8043x over previous
//
#include <hip/hip_runtime.h>

typedef __bf16 bf16x8 __attribute__((ext_vector_type(8)));
typedef float f32x4 __attribute__((ext_vector_type(4)));

#define GLDS(gp, lp) __builtin_amdgcn_global_load_lds( \
    (const __attribute__((address_space(1))) void*)(gp), \
    (__attribute__((address_space(3))) void*)(lp), 16, 0, 0)
#define WAITV(n) asm volatile("s_waitcnt vmcnt(" #n ")" ::: "memory")
#define MEMF() asm volatile("" ::: "memory")

__device__ __forceinline__ unsigned short f2bf(float f) {
    unsigned int u = __builtin_bit_cast(unsigned int, f);
    u += 0x7fffu + ((u >> 16) & 1u);
    return (unsigned short)(u >> 16);
}

// ---- Kernel 1: s_eff[b][i] = (style[b]·affine_w[i]/sqrt(S) + affine_b[i]) * wg ----
__global__ void k_style(const float* __restrict__ style, const float* __restrict__ aw,
                        const float* __restrict__ ab, float* __restrict__ s_eff) {
    int b = blockIdx.x;
    int i = threadIdx.x;
    __shared__ float st[512];
    st[i] = style[(b << 9) + i];
    __syncthreads();
    const float4* row = (const float4*)(aw + ((size_t)i << 9));
    float acc = 0.f;
#pragma unroll 4
    for (int k = 0; k < 128; ++k) {
        float4 r = row[k];
        acc += r.x * st[4 * k] + r.y * st[4 * k + 1] + r.z * st[4 * k + 2] + r.w * st[4 * k + 3];
    }
    float s = acc * 0.04419417382415922f + ab[i];
    s_eff[(b << 9) + i] = s * 0.014731391274719739f;
}

// ---- Kernel 2: zero ONLY the padding border of xmod ----
__global__ __launch_bounds__(256) void k_border(unsigned short* __restrict__ xmod) {
    int idx = blockIdx.x * 256 + threadIdx.x;
    int cell = idx >> 6, sub = idx & 63;
    int b = cell / 260, c = cell - b * 260;
    int row, col;
    if (c < 66)       { row = 0;  col = c; }
    else if (c < 132) { row = 65; col = c - 66; }
    else { int d = c - 132; row = 1 + (d >> 1); col = (d & 1) * 65; }
    uint4 z; z.x = z.y = z.z = z.w = 0u;
    *(uint4*)(xmod + (((size_t)(b * 66 + row) * 66 + col) << 9) + (sub << 3)) = z;
}

// ---- Kernel 3: x (NCHW f32) -> xmod (padded NHWC bf16), modulated ----
__global__ __launch_bounds__(256) void k_packx(const float* __restrict__ x,
                                               const float* __restrict__ s_eff,
                                               unsigned short* __restrict__ xmod) {
    int b = blockIdx.z, h = blockIdx.y, i0 = blockIdx.x << 6;
    __shared__ unsigned short tile[64][72];
    int t = threadIdx.x;
    int w4 = (t & 15) << 2;
    int ig = t >> 4;
#pragma unroll
    for (int r = 0; r < 4; ++r) {
        int il = (r << 4) + ig;
        int i = i0 + il;
        float4 v = *(const float4*)(x + (size_t)((((b << 9) + i) << 6) + h) * 64 + w4);
        float s = s_eff[(b << 9) + i];
        union { unsigned short us[4]; uint2 u2; } u;
        u.us[0] = f2bf(v.x * s); u.us[1] = f2bf(v.y * s);
        u.us[2] = f2bf(v.z * s); u.us[3] = f2bf(v.w * s);
        *(uint2*)&tile[il][w4] = u.u2;
    }
    __syncthreads();
    int ib = (t & 7) << 3;
    int wb = t >> 3;
#pragma unroll
    for (int pass = 0; pass < 2; ++pass) {
        int w = wb + (pass << 5);
        union { unsigned short us[8]; uint4 v; } u;
#pragma unroll
        for (int j = 0; j < 8; ++j) u.us[j] = tile[ib + j][w];
        *(uint4*)(xmod + (((size_t)(b * 66 + h + 1) * 66 + (w + 1)) << 9) + i0 + ib) = u.v;
    }
}

// ---- Kernel 4: weight (O,I,3,3 f32) -> wpk2 [O][ic 0..15][r 0..8][ch 0..31] bf16 ----
__global__ __launch_bounds__(256) void k_packw(const float* __restrict__ wsrc,
                                               unsigned short* __restrict__ wpk2) {
    int o = blockIdx.x;
    int t = threadIdx.x;
#pragma unroll
    for (int ii = 0; ii < 2; ++ii) {
        int i = t * 2 + ii;
        const float* src = wsrc + (size_t)(o * 512 + i) * 9;
        int ic = i >> 5, ch = i & 31;
        unsigned short* dst = wpk2 + (size_t)o * 4608 + ic * 288 + ch;
#pragma unroll
        for (int r = 0; r < 9; ++r)
            dst[r * 32] = f2bf(src[r]);
    }
}

// ---- Kernel 5: implicit GEMM conv, T3+T4 pipelined, T2 bank-swizzled. ----
// Tile 128(O) x 128(N = 2 rows x 64 w), 4 waves 2x2, 16x16x32 bf16 MFMA.
// 144 K-steps of 32. A: global_load_lds, triple-buffered, issued 2 steps ahead.
// B: global_load_lds, double-buffered per 32-ch chunk, issued 5 steps ahead (r==4).
// One raw barrier per step with COUNTED vmcnt (never drain-0 in the loop).
// Bank swizzle (both-sides): 16B slot ^= (row>>1)&3 (A) / (col>>1)&3 (B) so 8
// consecutive lanes of each ds_read_b128 cover all 8 bank-groups.
__global__ __launch_bounds__(256) void k_conv(const unsigned short* __restrict__ xmod,
                                              const unsigned short* __restrict__ wpk2,
                                              float* __restrict__ out) {
    // LDS: B 2 x 17408 (1056 real 16B-chunks + wave0 dummy tail), A 3 x 8192
    __shared__ __attribute__((aligned(128))) unsigned char lds[59392];
    unsigned char* Ab = lds + 34816;

    int bid = blockIdx.x;
    int swz = ((bid & 7) << 6) | (bid >> 3);     // XCD swizzle (512 = 8*64, bijective)
    int mt = swz >> 7, nt = swz & 127;
    int b = nt >> 5, h0 = (nt & 31) << 1;
    int m0 = mt << 7;
    int tid = threadIdx.x;
    int lane = tid & 63;
    int wv = tid >> 6;
    int wave_m = wv & 1, wave_n = wv >> 1;
    int lm = lane & 15, lk = lane >> 4;

    const unsigned char* xq = (const unsigned char*)xmod;
    const unsigned char* wq = (const unsigned char*)wpk2;

    // ---- per-thread global source offsets (pre-swizzled) ----
    int asrc0, asrc1;
    {
        int c0 = tid, r0 = c0 >> 2, j0 = (c0 & 3) ^ ((r0 >> 1) & 3);
        int c1 = 256 + tid, r1 = c1 >> 2, j1 = (c1 & 3) ^ ((r1 >> 1) & 3);
        asrc0 = (m0 + r0) * 9216 + (j0 << 4);
        asrc1 = (m0 + r1) * 9216 + (j1 << 4);
    }
    int bsrc[5];
#pragma unroll
    for (int q = 0; q < 5; ++q) {
        int c = q * 256 + tid; if (c > 1055) c = 1055;
        int cl = c >> 2, sub = c & 3;
        int row = cl / 66, col = cl - row * 66;
        int sub2 = sub ^ ((col >> 1) & 3);
        bsrc[q] = ((b * 66 + h0 + row) * 66 + col) * 1024 + (sub2 << 4);
    }

    // ---- LDS read offsets (swizzled slots) ----
    int aoff = ((wave_m << 6) + lm) * 64 + ((lk ^ ((lm >> 1) & 3)) << 4);   // + fm*1024
    int boff[4][3];
#pragma unroll
    for (int fn = 0; fn < 4; ++fn) {
        int nl = (wave_n << 6) + (fn << 4) + lm;
        int hl = nl >> 6, w = nl & 63;
#pragma unroll
        for (int kw = 0; kw < 3; ++kw) {
            int col = w + kw;
            boff[fn][kw] = hl * 4224 + col * 64 + ((lk ^ ((col >> 1) & 3)) << 4);  // + kh*4224
        }
    }

    f32x4 acc[4][4] = {};

    // ---- prologue: issue B[0], A[0], A[1] ----
    {
        unsigned char* bd = lds + wv * 1024;
        GLDS(xq + bsrc[0], bd);
        GLDS(xq + bsrc[1], bd + 4096);
        GLDS(xq + bsrc[2], bd + 8192);
        GLDS(xq + bsrc[3], bd + 12288);
        if (wv == 0) GLDS(xq + bsrc[4], lds + 16384);
        unsigned char* ad = Ab + wv * 1024;
        GLDS(wq + asrc0, ad);             GLDS(wq + asrc1, ad + 4096);
        GLDS(wq + asrc0 + 64, ad + 8192); GLDS(wq + asrc1 + 64, ad + 8192 + 4096);
    }

#pragma unroll 1
    for (int ic = 0; ic < 16; ++ic) {
        const unsigned char* Bb = lds + (ic & 1) * 17408;
        unsigned char* Bn = lds + ((ic + 1) & 1) * 17408;
#pragma unroll
        for (int r = 0; r < 9; ++r) {
            // counted wait: A[s] must have landed; at r=5,6 the younger B[ic+1] stays in flight
            if (r == 5 || r == 6) { if (wv == 0) { WAITV(7); } else { WAITV(6); } }
            else { WAITV(2); }
            __builtin_amdgcn_s_barrier();
            MEMF();
            // issue A[s+2] (dummy-safe past the end: wpk2 has 1KB slack)
            {
                int s2b = (ic * 9 + r + 2) << 6;
                unsigned char* ad = Ab + ((r + 2) % 3) * 8192 + wv * 1024;
                GLDS(wq + asrc0 + s2b, ad);
                GLDS(wq + asrc1 + s2b, ad + 4096);
            }
            if (r == 4) {   // issue B[ic+1], 5 steps ahead (ic=15 issues harmless dummy)
                int icb = (ic + 1) << 6;
                unsigned char* bd = Bn + wv * 1024;
                GLDS(xq + bsrc[0] + icb, bd);
                GLDS(xq + bsrc[1] + icb, bd + 4096);
                GLDS(xq + bsrc[2] + icb, bd + 8192);
                GLDS(xq + bsrc[3] + icb, bd + 12288);
                if (wv == 0) GLDS(xq + bsrc[4] + icb, Bn + 16384);
            }
            // compute step s from Abuf[r%3], Bb
            const unsigned char* Ar = Ab + (r % 3) * 8192;
            int kh = r / 3, kw = r - kh * 3;
            bf16x8 af[4], bfr[4];
#pragma unroll
            for (int fm = 0; fm < 4; ++fm)
                af[fm] = *(const bf16x8*)(Ar + aoff + fm * 1024);
#pragma unroll
            for (int fn = 0; fn < 4; ++fn)
                bfr[fn] = *(const bf16x8*)(Bb + boff[fn][kw] + kh * 4224);
            __builtin_amdgcn_s_setprio(1);
#pragma unroll
            for (int fm = 0; fm < 4; ++fm)
#pragma unroll
                for (int fn = 0; fn < 4; ++fn)
                    acc[fm][fn] = __builtin_amdgcn_mfma_f32_16x16x32_bf16(af[fm], bfr[fn], acc[fm][fn], 0, 0, 0);
            __builtin_amdgcn_s_setprio(0);
            MEMF();
        }
    }

    // ---- epilogue ----
#pragma unroll
    for (int fm = 0; fm < 4; ++fm) {
        int o = m0 + (wave_m << 6) + (fm << 4) + (lk << 2);
#pragma unroll
        for (int fn = 0; fn < 4; ++fn) {
            int nl = (wave_n << 6) + (fn << 4) + lm;
            int hl = nl >> 6, w = nl & 63;
            float* dst = out + ((((b << 9) + o) << 6) + (h0 + hl)) * 64 + w;
#pragma unroll
            for (int rr = 0; rr < 4; ++rr)
                dst[rr * 4096] = acc[fm][fn][rr];
        }
    }
}

extern "C" void kernel_launch(void* const* d_in, const int* in_sizes, int n_in,
                              void* d_out, int out_size, void* d_ws, size_t ws_size,
                              hipStream_t stream) {
    const float* x      = (const float*)d_in[0];
    const float* style  = (const float*)d_in[1];
    const float* weight = (const float*)d_in[2];
    const float* aff_w  = (const float*)d_in[3];
    const float* aff_b  = (const float*)d_in[4];
    float* out = (float*)d_out;

    unsigned short* xmod = (unsigned short*)d_ws;            // 17,842,176 B
    unsigned short* wpk2 = xmod + 8921088;                   // 4,718,592 B (+1KB slack after)
    float* s_eff = (float*)((char*)d_ws + 22561792);         // 2048 f32

    hipLaunchKernelGGL(k_style, dim3(4), dim3(512), 0, stream, style, aff_w, aff_b, s_eff);
    hipLaunchKernelGGL(k_border, dim3(260), dim3(256), 0, stream, xmod);
    hipLaunchKernelGGL(k_packx, dim3(8, 64, 4), dim3(256), 0, stream, x, s_eff, xmod);
    hipLaunchKernelGGL(k_packw, dim3(512), dim3(256), 0, stream, weight, wpk2);
    hipLaunchKernelGGL(k_conv, dim3(512), dim3(256), 0, stream, xmod, wpk2, out);
}

// Round 6
// 118.840 us; speedup vs baseline: 1.8075x; 1.0018x over previous
//
#include <hip/hip_runtime.h>

typedef __bf16 bf16x8 __attribute__((ext_vector_type(8)));
typedef float f32x4 __attribute__((ext_vector_type(4)));

#define GLDS(gp, lp) __builtin_amdgcn_global_load_lds( \
    (const __attribute__((address_space(1))) void*)(gp), \
    (__attribute__((address_space(3))) void*)(lp), 16, 0, 0)
#define WAITV(n) asm volatile("s_waitcnt vmcnt(" #n ")" ::: "memory")
#define MEMF() asm volatile("" ::: "memory")

__device__ __forceinline__ unsigned short f2bf(float f) {
    unsigned int u = __builtin_bit_cast(unsigned int, f);
    u += 0x7fffu + ((u >> 16) & 1u);
    return (unsigned short)(u >> 16);
}

// ---- Kernel 1: s_eff[b][i] = (style[b]·affine_w[i]/sqrt(S) + affine_b[i]) * wg ----
__global__ void k_style(const float* __restrict__ style, const float* __restrict__ aw,
                        const float* __restrict__ ab, float* __restrict__ s_eff) {
    int b = blockIdx.x;
    int i = threadIdx.x;
    __shared__ float st[512];
    st[i] = style[(b << 9) + i];
    __syncthreads();
    const float4* row = (const float4*)(aw + ((size_t)i << 9));
    float acc = 0.f;
#pragma unroll 4
    for (int k = 0; k < 128; ++k) {
        float4 r = row[k];
        acc += r.x * st[4 * k] + r.y * st[4 * k + 1] + r.z * st[4 * k + 2] + r.w * st[4 * k + 3];
    }
    float s = acc * 0.04419417382415922f + ab[i];
    s_eff[(b << 9) + i] = s * 0.014731391274719739f;
}

// ---- Kernel 2: zero ONLY the padding border of xmod ----
__global__ __launch_bounds__(256) void k_border(unsigned short* __restrict__ xmod) {
    int idx = blockIdx.x * 256 + threadIdx.x;
    int cell = idx >> 6, sub = idx & 63;
    int b = cell / 260, c = cell - b * 260;
    int row, col;
    if (c < 66)       { row = 0;  col = c; }
    else if (c < 132) { row = 65; col = c - 66; }
    else { int d = c - 132; row = 1 + (d >> 1); col = (d & 1) * 65; }
    uint4 z; z.x = z.y = z.z = z.w = 0u;
    *(uint4*)(xmod + (((size_t)(b * 66 + row) * 66 + col) << 9) + (sub << 3)) = z;
}

// ---- Kernel 3: x (NCHW f32) -> xmod (padded NHWC bf16), modulated. LDS-free reg transpose. ----
__global__ __launch_bounds__(256) void k_packx(const float* __restrict__ x,
                                               const float* __restrict__ s_eff,
                                               unsigned short* __restrict__ xmod) {
    int b = blockIdx.z, h = blockIdx.y, i0 = blockIdx.x << 6;
    int t = threadIdx.x;
    int cq = t & 15;     // channel quad (4 ch)
    int wg = t >> 4;     // w-group of 4
    unsigned short rows[4][4];
#pragma unroll
    for (int j = 0; j < 4; ++j) {
        int i = i0 + (cq << 2) + j;
        float4 v = *(const float4*)(x + (size_t)((((b << 9) + i) << 6) + h) * 64 + (wg << 2));
        float s = s_eff[(b << 9) + i];
        rows[j][0] = f2bf(v.x * s); rows[j][1] = f2bf(v.y * s);
        rows[j][2] = f2bf(v.z * s); rows[j][3] = f2bf(v.w * s);
    }
#pragma unroll
    for (int k = 0; k < 4; ++k) {
        union { unsigned short us[4]; uint2 u; } u;
#pragma unroll
        for (int j = 0; j < 4; ++j) u.us[j] = rows[j][k];
        int col = (wg << 2) + k + 1;
        *(uint2*)(xmod + (((size_t)(b * 66 + h + 1) * 66 + col) << 9) + i0 + (cq << 2)) = u.u;
    }
}

// ---- Kernel 4: weight (O,I,3,3 f32) -> wpk3 fragment-linear: [mt][s=ic*9+r][wm*4+fm][lane][8ch] ----
// For step s, a wave's af[fm] load = base + s*8KB + (wm*4+fm)*1KB + lane*16B : perfectly coalesced.
__global__ __launch_bounds__(256) void k_packw(const float* __restrict__ wsrc,
                                               unsigned short* __restrict__ wpk3) {
    int o = blockIdx.x;
    int t = threadIdx.x;
    int mt = o >> 7, wm = (o >> 6) & 1, fm = (o >> 4) & 3, lm = o & 15;
    size_t obase = ((size_t)mt * 144) * 4096 + (((wm << 2) + fm) << 9) + (lm << 3);
#pragma unroll
    for (int ii = 0; ii < 2; ++ii) {
        int i = (t << 1) + ii;
        const float* src = wsrc + (size_t)((o << 9) + i) * 9;
        int ic = i >> 5, lk = (i >> 3) & 3, chsub = i & 7;
        unsigned short* dst = wpk3 + obase + (size_t)ic * 9 * 4096 + (lk << 7) + chsub;
#pragma unroll
        for (int r = 0; r < 9; ++r)
            dst[r * 4096] = f2bf(src[r]);
    }
}

// ---- Kernel 5: implicit GEMM conv. A in REGISTERS (L2-resident, fragment-linear), B in LDS. ----
// Tile 128(O) x 128(N = 2 rows x 64 w), 4 waves 2x2, 16x16x32 bf16 MFMA, 144 K-steps.
// A: coalesced global->VGPR, 3-slot rotation, prefetched 2 steps ahead (compiler-managed waits).
// B: global_load_lds double-buffer, issued 5 steps ahead (r==4), bank-swizzled (T2).
// ONE barrier + WAITV(4) per 32-ch chunk (16 total). setprio around MFMA cluster (T5).
__global__ __launch_bounds__(256, 2) void k_conv(const unsigned short* __restrict__ xmod,
                                                 const unsigned short* __restrict__ wpk3,
                                                 float* __restrict__ out) {
    __shared__ __attribute__((aligned(128))) unsigned char lds[2][17408];

    int bid = blockIdx.x;
    int swz = ((bid & 7) << 6) | (bid >> 3);     // XCD swizzle (512 = 8*64, bijective)
    int mt = swz >> 7, nt = swz & 127;
    int b = nt >> 5, h0 = (nt & 31) << 1;
    int m0 = mt << 7;
    int tid = threadIdx.x;
    int lane = tid & 63;
    int wv = tid >> 6;
    int wave_m = wv & 1, wave_n = wv >> 1;
    int lm = lane & 15, lk = lane >> 4;

    const unsigned char* xq = (const unsigned char*)xmod;

    // B global source offsets (pre-swizzled: slot ^= (col>>1)&3)
    int bsrc[5];
#pragma unroll
    for (int q = 0; q < 5; ++q) {
        int c = q * 256 + tid; if (c > 1055) c = 1055;
        int cl = c >> 2, sub = c & 3;
        int row = cl / 66, col = cl - row * 66;
        int sub2 = sub ^ ((col >> 1) & 3);
        bsrc[q] = ((b * 66 + h0 + row) * 66 + col) * 1024 + (sub2 << 4);
    }

    // B LDS read offsets (swizzled slots)
    int boff[4][3];
#pragma unroll
    for (int fn = 0; fn < 4; ++fn) {
        int nl = (wave_n << 6) + (fn << 4) + lm;
        int hl = nl >> 6, w = nl & 63;
#pragma unroll
        for (int kw = 0; kw < 3; ++kw) {
            int col = w + kw;
            boff[fn][kw] = hl * 4224 + col * 64 + ((lk ^ ((col >> 1) & 3)) << 4);  // + kh*4224
        }
    }

    // A fragment stream: per step s, af[fm] = abase + s*4096 + fm*512 (elements)
    const unsigned short* abase = wpk3 + ((size_t)mt * 144) * 4096 + ((wave_m << 2) << 9) + (lane << 3);

    f32x4 acc[4][4] = {};
    bf16x8 af[3][4];

    // ---- prologue: issue B[0] (GLDS), load A[0],A[1] to regs ----
    {
        unsigned char* bd = &lds[0][0] + wv * 1024;
        GLDS(xq + bsrc[0], bd);
        GLDS(xq + bsrc[1], bd + 4096);
        GLDS(xq + bsrc[2], bd + 8192);
        GLDS(xq + bsrc[3], bd + 12288);
        if (wv == 0) GLDS(xq + bsrc[4], &lds[0][0] + 16384);
    }
#pragma unroll
    for (int fm = 0; fm < 4; ++fm) af[0][fm] = *(const bf16x8*)(abase + fm * 512);
#pragma unroll
    for (int fm = 0; fm < 4; ++fm) af[1][fm] = *(const bf16x8*)(abase + 4096 + fm * 512);

#pragma unroll 1
    for (int ic = 0; ic < 16; ++ic) {
        const unsigned char* Bb = &lds[ic & 1][0];
        unsigned char* Bn = &lds[(ic + 1) & 1][0];
#pragma unroll
        for (int r = 0; r < 9; ++r) {
            if (r == 0) {
                // own B chunks + A[t] are older than A[t+1]'s 4 loads -> <=4 outstanding proves both landed
                WAITV(4);
                __builtin_amdgcn_s_barrier();
                MEMF();
            }
            int s = ic * 9 + r;
            // prefetch A[s+2] into rotation slot (r+2)%3  (9 % 3 == 0 -> ic-invariant)
            {
                const unsigned short* ap = abase + (size_t)(s + 2) * 4096;
#pragma unroll
                for (int fm = 0; fm < 4; ++fm)
                    af[(r + 2) % 3][fm] = *(const bf16x8*)(ap + fm * 512);
            }
            if (r == 4) {   // issue B[ic+1], 5 steps ahead (ic=15 issues harmless dummy)
                int icb = (ic + 1) << 6;
                unsigned char* bd = Bn + wv * 1024;
                GLDS(xq + bsrc[0] + icb, bd);
                GLDS(xq + bsrc[1] + icb, bd + 4096);
                GLDS(xq + bsrc[2] + icb, bd + 8192);
                GLDS(xq + bsrc[3] + icb, bd + 12288);
                if (wv == 0) GLDS(xq + bsrc[4] + icb, Bn + 16384);
            }
            int kh = r / 3, kw = r - kh * 3;
            bf16x8 bfr[4];
#pragma unroll
            for (int fn = 0; fn < 4; ++fn)
                bfr[fn] = *(const bf16x8*)(Bb + boff[fn][kw] + kh * 4224);
            __builtin_amdgcn_s_setprio(1);
#pragma unroll
            for (int fm = 0; fm < 4; ++fm)
#pragma unroll
                for (int fn = 0; fn < 4; ++fn)
                    acc[fm][fn] = __builtin_amdgcn_mfma_f32_16x16x32_bf16(af[r % 3][fm], bfr[fn], acc[fm][fn], 0, 0, 0);
            __builtin_amdgcn_s_setprio(0);
            MEMF();
        }
    }

    // ---- epilogue ----
#pragma unroll
    for (int fm = 0; fm < 4; ++fm) {
        int o = m0 + (wave_m << 6) + (fm << 4) + (lk << 2);
#pragma unroll
        for (int fn = 0; fn < 4; ++fn) {
            int nl = (wave_n << 6) + (fn << 4) + lm;
            int hl = nl >> 6, w = nl & 63;
            float* dst = out + ((((b << 9) + o) << 6) + (h0 + hl)) * 64 + w;
#pragma unroll
            for (int rr = 0; rr < 4; ++rr)
                dst[rr * 4096] = acc[fm][fn][rr];
        }
    }
}

extern "C" void kernel_launch(void* const* d_in, const int* in_sizes, int n_in,
                              void* d_out, int out_size, void* d_ws, size_t ws_size,
                              hipStream_t stream) {
    const float* x      = (const float*)d_in[0];
    const float* style  = (const float*)d_in[1];
    const float* weight = (const float*)d_in[2];
    const float* aff_w  = (const float*)d_in[3];
    const float* aff_b  = (const float*)d_in[4];
    float* out = (float*)d_out;

    unsigned short* xmod = (unsigned short*)d_ws;            // 17,842,176 B
    unsigned short* wpk3 = xmod + 8921088;                   // 4,718,592 B (+16KB slack for tail prefetch)
    float* s_eff = (float*)((char*)d_ws + 22577152);         // 2048 f32

    hipLaunchKernelGGL(k_style, dim3(4), dim3(512), 0, stream, style, aff_w, aff_b, s_eff);
    hipLaunchKernelGGL(k_border, dim3(260), dim3(256), 0, stream, xmod);
    hipLaunchKernelGGL(k_packx, dim3(8, 64, 4), dim3(256), 0, stream, x, s_eff, xmod);
    hipLaunchKernelGGL(k_packw, dim3(512), dim3(256), 0, stream, weight, wpk3);
    hipLaunchKernelGGL(k_conv, dim3(512), dim3(256), 0, stream, xmod, wpk3, out);
}

// Round 7
// 115.614 us; speedup vs baseline: 1.8580x; 1.0279x over previous
//
#include <hip/hip_runtime.h>

typedef __bf16 bf16x8 __attribute__((ext_vector_type(8)));
typedef float f32x4 __attribute__((ext_vector_type(4)));

#define GLDS(gp, lp) __builtin_amdgcn_global_load_lds( \
    (const __attribute__((address_space(1))) void*)(gp), \
    (__attribute__((address_space(3))) void*)(lp), 16, 0, 0)
#define WAITV(n) asm volatile("s_waitcnt vmcnt(" #n ")" ::: "memory")
#define MEMF() asm volatile("" ::: "memory")

__device__ __forceinline__ unsigned short f2bf(float f) {
    unsigned int u = __builtin_bit_cast(unsigned int, f);
    u += 0x7fffu + ((u >> 16) & 1u);
    return (unsigned short)(u >> 16);
}

// ---- Fused prep kernel: style (blocks 0..3), border-zero (4..133), packw (134..645) ----
__global__ __launch_bounds__(512) void k_prep(const float* __restrict__ style,
                                              const float* __restrict__ aw,
                                              const float* __restrict__ ab,
                                              const float* __restrict__ wsrc,
                                              float* __restrict__ s_eff,
                                              unsigned short* __restrict__ xmod,
                                              unsigned short* __restrict__ wpk3) {
    int bid = blockIdx.x, t = threadIdx.x;
    if (bid < 4) {
        // s_eff[b][i] = (style[b]·affine_w[i]/sqrt(S) + affine_b[i]) * wg
        int b = bid, i = t;
        __shared__ float st[512];
        st[i] = style[(b << 9) + i];
        __syncthreads();
        const float4* row = (const float4*)(aw + ((size_t)i << 9));
        float acc = 0.f;
#pragma unroll 4
        for (int k = 0; k < 128; ++k) {
            float4 r = row[k];
            acc += r.x * st[4 * k] + r.y * st[4 * k + 1] + r.z * st[4 * k + 2] + r.w * st[4 * k + 3];
        }
        float s = acc * 0.04419417382415922f + ab[i];
        s_eff[(b << 9) + i] = s * 0.014731391274719739f;
    } else if (bid < 134) {
        // zero padding border of xmod: 4 * 260 cells * 64 ch-chunks
        int idx = (bid - 4) * 512 + t;          // 0..66559
        int cell = idx >> 6, sub = idx & 63;
        int b = cell / 260, c = cell - b * 260;
        int row, col;
        if (c < 66)       { row = 0;  col = c; }
        else if (c < 132) { row = 65; col = c - 66; }
        else { int d = c - 132; row = 1 + (d >> 1); col = (d & 1) * 65; }
        uint4 z; z.x = z.y = z.z = z.w = 0u;
        *(uint4*)(xmod + (((size_t)(b * 66 + row) * 66 + col) << 9) + (sub << 3)) = z;
    } else {
        // weight (O,I,3,3 f32) -> wpk3 fragment-linear [mt][s=ic*9+r][(wm*4+fm)][lane][8ch]
        int o = bid - 134;
        int mt = o >> 7, wm = (o >> 6) & 1, fm = (o >> 4) & 3, lm = o & 15;
        size_t obase = ((size_t)mt * 144) * 4096 + (((wm << 2) + fm) << 9) + (lm << 3);
        int i = t;                               // input channel 0..511
        const float* src = wsrc + (size_t)((o << 9) + i) * 9;
        int ic = i >> 5, lk = (i >> 3) & 3, chsub = i & 7;
        unsigned short* dst = wpk3 + obase + (size_t)ic * 9 * 4096 + (lk << 7) + chsub;
#pragma unroll
        for (int r = 0; r < 9; ++r)
            dst[r * 4096] = f2bf(src[r]);
    }
}

// ---- packx: x (NCHW f32) -> xmod (padded NHWC bf16), modulated. LDS-free reg transpose. ----
__global__ __launch_bounds__(256) void k_packx(const float* __restrict__ x,
                                               const float* __restrict__ s_eff,
                                               unsigned short* __restrict__ xmod) {
    int b = blockIdx.z, h = blockIdx.y, i0 = blockIdx.x << 6;
    int t = threadIdx.x;
    int cq = t & 15;     // channel quad (4 ch)
    int wg = t >> 4;     // w-group of 4
    unsigned short rows[4][4];
#pragma unroll
    for (int j = 0; j < 4; ++j) {
        int i = i0 + (cq << 2) + j;
        float4 v = *(const float4*)(x + (size_t)((((b << 9) + i) << 6) + h) * 64 + (wg << 2));
        float s = s_eff[(b << 9) + i];
        rows[j][0] = f2bf(v.x * s); rows[j][1] = f2bf(v.y * s);
        rows[j][2] = f2bf(v.z * s); rows[j][3] = f2bf(v.w * s);
    }
#pragma unroll
    for (int k = 0; k < 4; ++k) {
        union { unsigned short us[4]; uint2 u; } u;
#pragma unroll
        for (int j = 0; j < 4; ++j) u.us[j] = rows[j][k];
        int col = (wg << 2) + k + 1;
        *(uint2*)(xmod + (((size_t)(b * 66 + h + 1) * 66 + col) << 9) + i0 + (cq << 2)) = u.u;
    }
}

// ---- k_conv: implicit GEMM. Block 128(O) x 256(N = 4 rows x 64 w), 4 waves of 64x128. ----
// Grid 256 = 1 block/CU. A: coalesced global->VGPR (L2-resident), 3-slot rotation, 2 ahead.
// B: global_load_lds double-buffer (6 rows x 66 cols x 64B = 25344 B/buf), issued at r==4,
// T2 both-sides swizzle. ONE barrier + WAITV(4) per 32-ch chunk. Per-CU-step walls:
// MFMA 621 cyc > LDS-B 376 > L2-A 285  => MFMA-bound by design.
__global__ __launch_bounds__(256, 1) void k_conv(const unsigned short* __restrict__ xmod,
                                                 const unsigned short* __restrict__ wpk3,
                                                 float* __restrict__ out) {
    __shared__ __attribute__((aligned(128))) unsigned char lds[2][25344];

    int bid = blockIdx.x;
    int swz = ((bid & 7) << 5) | (bid >> 3);     // XCD swizzle (256 = 8*32, bijective)
    int mt = swz >> 6, nt = swz & 63;            // mt 0..3, nt 0..63
    int b = nt >> 4, h0 = (nt & 15) << 2;        // 4 output rows per block
    int m0 = mt << 7;
    int tid = threadIdx.x;
    int lane = tid & 63;
    int wv = tid >> 6;
    int wave_m = wv & 1, wave_n = wv >> 1;       // wave tile 64(M) x 128(N)
    int lm = lane & 15, lk = lane >> 4;

    const unsigned char* xq = (const unsigned char*)xmod;

    // B global source offsets (pre-swizzled: 16B slot ^= (col>>1)&3). 1584 chunks, 7 rounds.
    int bsrc[7];
#pragma unroll
    for (int q = 0; q < 7; ++q) {
        int c = q * 256 + tid; if (c > 1583) c = 1583;
        int cl = c >> 2, sub = c & 3;
        int row = cl / 66, col = cl - row * 66;
        int sub2 = sub ^ ((col >> 1) & 3);
        bsrc[q] = ((b * 66 + h0 + row) * 66 + col) * 1024 + (sub2 << 4);
    }

    // B LDS read offsets (swizzled slots). fn 0..7 covers N=128 = rows (wave_n*2 + nl>>6), w = nl&63.
    int boff[8][3];
#pragma unroll
    for (int fn = 0; fn < 8; ++fn) {
        int nl = (wave_n << 7) + (fn << 4) + lm;
        int hl = nl >> 6, w = nl & 63;
#pragma unroll
        for (int kw = 0; kw < 3; ++kw) {
            int col = w + kw;
            boff[fn][kw] = hl * 4224 + col * 64 + ((lk ^ ((col >> 1) & 3)) << 4);  // + kh*4224
        }
    }

    // A fragment stream: per step s, af[fm] = abase + s*4096 + fm*512 (elements)
    const unsigned short* abase = wpk3 + ((size_t)mt * 144) * 4096 + ((wave_m << 2) << 9) + (lane << 3);

    f32x4 acc[4][8] = {};
    bf16x8 af[3][4];

    // ---- prologue: issue B[0] (GLDS, linear dest = chunk*16), load A[0],A[1] to regs ----
    {
        unsigned char* bd = &lds[0][0] + tid * 16;
#pragma unroll
        for (int q = 0; q < 7; ++q) {
            if (q * 256 + tid < 1584) GLDS(xq + bsrc[q], bd + q * 4096);
        }
    }
#pragma unroll
    for (int fm = 0; fm < 4; ++fm) af[0][fm] = *(const bf16x8*)(abase + fm * 512);
#pragma unroll
    for (int fm = 0; fm < 4; ++fm) af[1][fm] = *(const bf16x8*)(abase + 4096 + fm * 512);

#pragma unroll 1
    for (int ic = 0; ic < 16; ++ic) {
        const unsigned char* Bb = &lds[ic & 1][0];
        unsigned char* Bn = &lds[(ic + 1) & 1][0];
#pragma unroll
        for (int r = 0; r < 9; ++r) {
            if (r == 0) {
                // B[ic] chunks + A[s] are older than A[s+1]'s 4 loads -> <=4 outstanding proves both done
                WAITV(4);
                __builtin_amdgcn_s_barrier();
                MEMF();
            }
            int s = ic * 9 + r;
            // prefetch A[s+2] into rotation slot (r+2)%3  (9 % 3 == 0 -> ic-invariant)
            {
                const unsigned short* ap = abase + (size_t)(s + 2) * 4096;
#pragma unroll
                for (int fm = 0; fm < 4; ++fm)
                    af[(r + 2) % 3][fm] = *(const bf16x8*)(ap + fm * 512);
            }
            if (r == 4) {   // issue B[ic+1] (ic=15 issues harmless dummy into dead buffer)
                int icb = (ic + 1) << 6;
                unsigned char* bd = Bn + tid * 16;
#pragma unroll
                for (int q = 0; q < 7; ++q) {
                    if (q * 256 + tid < 1584) GLDS(xq + bsrc[q] + icb, bd + q * 4096);
                }
            }
            int kh = r / 3, kw = r - kh * 3;
            bf16x8 bfr[8];
#pragma unroll
            for (int fn = 0; fn < 8; ++fn)
                bfr[fn] = *(const bf16x8*)(Bb + boff[fn][kw] + kh * 4224);
#pragma unroll
            for (int fm = 0; fm < 4; ++fm)
#pragma unroll
                for (int fn = 0; fn < 8; ++fn)
                    acc[fm][fn] = __builtin_amdgcn_mfma_f32_16x16x32_bf16(af[r % 3][fm], bfr[fn], acc[fm][fn], 0, 0, 0);
            MEMF();
        }
    }

    // ---- epilogue: D row=(lk*4+rr) is O-sub, col=lm indexes N ----
#pragma unroll
    for (int fm = 0; fm < 4; ++fm) {
        int o = m0 + (wave_m << 6) + (fm << 4) + (lk << 2);
#pragma unroll
        for (int fn = 0; fn < 8; ++fn) {
            int nl = (wave_n << 7) + (fn << 4) + lm;
            int hl = nl >> 6, w = nl & 63;
            float* dst = out + ((((b << 9) + o) << 6) + (h0 + hl)) * 64 + w;
#pragma unroll
            for (int rr = 0; rr < 4; ++rr)
                dst[rr * 4096] = acc[fm][fn][rr];
        }
    }
}

extern "C" void kernel_launch(void* const* d_in, const int* in_sizes, int n_in,
                              void* d_out, int out_size, void* d_ws, size_t ws_size,
                              hipStream_t stream) {
    const float* x      = (const float*)d_in[0];
    const float* style  = (const float*)d_in[1];
    const float* weight = (const float*)d_in[2];
    const float* aff_w  = (const float*)d_in[3];
    const float* aff_b  = (const float*)d_in[4];
    float* out = (float*)d_out;

    unsigned short* xmod = (unsigned short*)d_ws;            // 17,842,176 B
    unsigned short* wpk3 = xmod + 8921088;                   // 4,718,592 B (+16KB slack for tail prefetch)
    float* s_eff = (float*)((char*)d_ws + 22577152);         // 2048 f32

    hipLaunchKernelGGL(k_prep, dim3(646), dim3(512), 0, stream,
                       style, aff_w, aff_b, weight, s_eff, xmod, wpk3);
    hipLaunchKernelGGL(k_packx, dim3(8, 64, 4), dim3(256), 0, stream, x, s_eff, xmod);
    hipLaunchKernelGGL(k_conv, dim3(256), dim3(256), 0, stream, xmod, wpk3, out);
}